// Round 7
// baseline (417.076 us; speedup 1.0000x reference)
//
#include <hip/hip_runtime.h>
#include <hip/hip_bf16.h>

typedef unsigned int u32;
typedef unsigned short u16;
typedef __attribute__((ext_vector_type(8))) short bf16x8;
typedef __attribute__((ext_vector_type(4))) float f32x4;

__device__ __forceinline__ float u16tof(u16 u){ return __uint_as_float(((u32)u) << 16); }
__device__ __forceinline__ float lo16(u32 v){ return __uint_as_float(v << 16); }
__device__ __forceinline__ float hi16(u32 v){ return __uint_as_float(v & 0xffff0000u); }
__device__ __forceinline__ u16 ftobf(float f){
  u32 b = __float_as_uint(f);
  return (u16)((b + 0x7FFFu + ((b >> 16) & 1u)) >> 16);
}
__device__ __forceinline__ u32 pack2(float a, float b){
  return (u32)ftobf(a) | ((u32)ftobf(b) << 16);
}
__device__ __forceinline__ float ldf(const void* p, int i, int isbf){
  return isbf ? u16tof(((const u16*)p)[i]) : ((const float*)p)[i];
}

// ---- fused prep: blocks 0..L do dtype-detect + fragment-order weights;
//      blocks L+1.. convert x -> bf16 Hb (fp32 path only; self-detect cheaply) ----
__global__ __launch_bounds__(256) void k_prep(const void* __restrict__ gw, const void* __restrict__ l1w,
                                              const void* __restrict__ x, u16* __restrict__ Wf,
                                              u16* __restrict__ Hb, int L, int n8, int* __restrict__ flag){
  const int b = blockIdx.x;
  __shared__ int cnt;
  if (threadIdx.x == 0) cnt = 0;
  __syncthreads();
  if (b <= L){
    // full detect on 4096 words of gw
    int local = 0;
    for (int i = threadIdx.x; i < 4096; i += 256){
      u32 e = (((const u32*)gw)[i] >> 7) & 0xFFu;
      if (e >= 100u && e < 127u) local++;
    }
    atomicAdd(&cnt, local);
    __syncthreads();
    const int isbf = (cnt > 2048) ? 1 : 0;
    if (b == 0 && threadIdx.x == 0) *flag = isbf;

    const void* src = (b < L) ? gw : l1w;
    const int sbase = (b < L) ? b * 16384 : 0;
    u16* dst = Wf + (size_t)b * 16384;
    for (int g = threadIdx.x; g < 2048; g += 256){
      const int t = g >> 8, ks = (g >> 6) & 3, lane = g & 63;
      const int n = t * 16 + (lane & 15);
      const int k0 = ks * 32 + ((lane >> 4) << 3);
      u16* d = dst + (size_t)g * 8;
      #pragma unroll
      for (int j = 0; j < 8; ++j){
        d[j] = ftobf(ldf(src, sbase + (k0 + j) * 128 + n, isbf));
      }
    }
  } else {
    // cheap detect: 256 samples of gw, clearly separated (bf16 ~256 hits, fp32 ~27)
    u32 e = (((const u32*)gw)[threadIdx.x] >> 7) & 0xFFu;
    atomicAdd(&cnt, (e >= 100u && e < 127u) ? 1 : 0);
    __syncthreads();
    if (cnt > 128) return;            // bf16 path: k_mm reads x directly
    const int i = (b - (L + 1)) * 256 + threadIdx.x;
    if (i >= n8) return;
    const float4 a = ((const float4*)x)[i * 2];
    const float4 c = ((const float4*)x)[i * 2 + 1];
    u16* o = Hb + (size_t)i * 8;
    o[0] = ftobf(a.x); o[1] = ftobf(a.y); o[2] = ftobf(a.z); o[3] = ftobf(a.w);
    o[4] = ftobf(c.x); o[5] = ftobf(c.y); o[6] = ftobf(c.z); o[7] = ftobf(c.w);
  }
}

// ---- degree count over dst ----
__global__ __launch_bounds__(256) void k_count(const int* __restrict__ dst, int* __restrict__ cnt, int nE){
  int i = blockIdx.x * 256 + threadIdx.x;
  if (i < nE) atomicAdd(&cnt[dst[i]], 1);
}

// ---- exclusive scan of cnt -> boff (block-local) ; also dinv = rsqrt(cnt+1) ----
__global__ __launch_bounds__(256) void k_scan1(const int* __restrict__ cnt, int* __restrict__ boff,
                                               int* __restrict__ bsum, float* __restrict__ dinv, int n){
  __shared__ int sm[256];
  int t = threadIdx.x;
  int i = blockIdx.x * 256 + t;
  int v = (i < n) ? cnt[i] : 0;
  if (i < n) dinv[i] = rsqrtf((float)v + 1.0f);
  sm[t] = v; __syncthreads();
  for (int off = 1; off < 256; off <<= 1){
    int add = (t >= off) ? sm[t - off] : 0;
    __syncthreads();
    sm[t] += add;
    __syncthreads();
  }
  if (i < n) boff[i] = sm[t] - v;
  if (t == 255) bsum[blockIdx.x] = sm[255];
}

// ---- boff fixup (each block redundantly scans bsum, nb<=512) + goff build ----
__global__ __launch_bounds__(256) void k_scan3(int* __restrict__ boff, const int* __restrict__ bsum, int nb,
                                               int n, int nE, const int* __restrict__ batch,
                                               int* __restrict__ goff, int G){
  __shared__ int sm[512];
  const int t = threadIdx.x;
  sm[t]       = (t < nb)       ? bsum[t]       : 0;
  sm[t + 256] = (t + 256 < nb) ? bsum[t + 256] : 0;
  __syncthreads();
  for (int off = 1; off < 512; off <<= 1){
    int v0 = (t >= off)       ? sm[t - off]       : 0;
    int v1 = (t + 256 >= off) ? sm[t + 256 - off] : 0;
    __syncthreads();
    sm[t] += v0; sm[t + 256] += v1;
    __syncthreads();
  }
  const int base = (blockIdx.x == 0) ? 0 : sm[blockIdx.x - 1];

  int i = blockIdx.x * 256 + t;
  if (i >= n) return;
  boff[i] += base;
  if (i == 0) boff[n] = nE;
  int b = batch[i];
  int prev = (i == 0) ? -1 : batch[i - 1];
  for (int g = prev + 1; g <= b; ++g) goff[g] = i;
  if (i == n - 1){
    for (int g = b + 1; g <= G; ++g) goff[g] = n;
  }
}

// ---- counting-sort edges by dst: eid[slot] = src ----
__global__ __launch_bounds__(256) void k_fill(const int* __restrict__ src, const int* __restrict__ dst,
                                              int* __restrict__ cnt, const int* __restrict__ boff,
                                              int* __restrict__ eid, int nE){
  int e = blockIdx.x * 256 + threadIdx.x;
  if (e >= nE) return;
  int d = dst[e];
  int old = atomicSub(&cnt[d], 1);
  eid[boff[d] + old - 1] = src[e];
}

// ---- GCN matmul: Ts[n,128] = (A[n,128] @ W) * dinv[row], bf16 out ----
// 32 rows/wave (2 row-tiles share each B-frag), LDS-repacked coalesced stores.
__global__ __launch_bounds__(256) void k_mm(const void* __restrict__ X, const u16* __restrict__ Hb, int use_x,
                                            const u16* __restrict__ Wf, const float* __restrict__ dinv,
                                            u16* __restrict__ T, int n, const int* __restrict__ fl){
  __shared__ u16 sm[4][32 * 132];
  const int isbf = *fl;
  const u16* A = (use_x && isbf) ? (const u16*)X : Hb;
  const int wave = threadIdx.x >> 6, lane = threadIdx.x & 63;
  const int m0 = blockIdx.x * 128 + wave * 32;
  int ar0 = m0 + (lane & 15);      if (ar0 > n - 1) ar0 = n - 1;
  int ar1 = m0 + 16 + (lane & 15); if (ar1 > n - 1) ar1 = n - 1;
  const u16* ap0 = A + (size_t)ar0 * 128 + ((lane >> 4) << 3);
  const u16* ap1 = A + (size_t)ar1 * 128 + ((lane >> 4) << 3);

  f32x4 acc0[8], acc1[8];
  #pragma unroll
  for (int t = 0; t < 8; ++t){ acc0[t] = (f32x4){0.f,0.f,0.f,0.f}; acc1[t] = (f32x4){0.f,0.f,0.f,0.f}; }

  #pragma unroll
  for (int ks = 0; ks < 4; ++ks){
    const bf16x8 a0 = *(const bf16x8*)(ap0 + ks * 32);
    const bf16x8 a1 = *(const bf16x8*)(ap1 + ks * 32);
    #pragma unroll
    for (int t = 0; t < 8; ++t){
      const bf16x8 b = *(const bf16x8*)(Wf + (size_t)(((t * 4 + ks) * 64 + lane) * 8));
      acc0[t] = __builtin_amdgcn_mfma_f32_16x16x32_bf16(a0, b, acc0[t], 0, 0, 0);
      acc1[t] = __builtin_amdgcn_mfma_f32_16x16x32_bf16(a1, b, acc1[t], 0, 0, 0);
    }
  }

  const int quad = lane >> 4, col0 = lane & 15;
  float dv0[4], dv1[4];
  #pragma unroll
  for (int r = 0; r < 4; ++r){
    const int r0 = m0 + quad * 4 + r;
    const int r1 = m0 + 16 + quad * 4 + r;
    dv0[r] = (r0 < n) ? dinv[r0] : 0.f;
    dv1[r] = (r1 < n) ? dinv[r1] : 0.f;
  }
  u16* my = sm[wave];
  #pragma unroll
  for (int t = 0; t < 8; ++t){
    #pragma unroll
    for (int r = 0; r < 4; ++r){
      my[(quad * 4 + r) * 132 + t * 16 + col0]        = ftobf(acc0[t][r] * dv0[r]);
      my[(16 + quad * 4 + r) * 132 + t * 16 + col0]   = ftobf(acc1[t][r] * dv1[r]);
    }
  }
  // wave-private LDS region: no __syncthreads needed (compiler inserts lgkmcnt waits)
  #pragma unroll
  for (int i = 0; i < 8; ++i){
    const int row = i * 4 + (lane >> 4);
    const int grow = m0 + row;
    const int c8 = (lane & 15) * 8;
    if (grow < n){
      const u16* s = &my[row * 132 + c8];
      uint2 lo = *(const uint2*)(s);
      uint2 hi = *(const uint2*)(s + 4);
      *(uint4*)&T[(size_t)grow * 128 + c8] = make_uint4(lo.x, lo.y, hi.x, hi.y);
    }
  }
}

// ---- fused head: s = relu(A@W1 + b1).w2 + b2, mask, write s (no atomics) ----
__global__ __launch_bounds__(256) void k_mmhead(const u16* __restrict__ Hb, const u16* __restrict__ Wf,
                                                const void* __restrict__ b1, const void* __restrict__ w2,
                                                const void* __restrict__ b2, const int* __restrict__ mask,
                                                float* __restrict__ s, int n, const int* __restrict__ fl){
  const int isbf = *fl;
  const int wave = threadIdx.x >> 6, lane = threadIdx.x & 63;
  const int m0 = blockIdx.x * 64 + wave * 16;
  int arow = m0 + (lane & 15); if (arow > n - 1) arow = n - 1;
  const u16* aptr = Hb + (size_t)arow * 128 + ((lane >> 4) << 3);

  f32x4 acc[8];
  #pragma unroll
  for (int t = 0; t < 8; ++t) acc[t] = (f32x4){0.f, 0.f, 0.f, 0.f};

  #pragma unroll
  for (int ks = 0; ks < 4; ++ks){
    const bf16x8 a = *(const bf16x8*)(aptr + ks * 32);
    #pragma unroll
    for (int t = 0; t < 8; ++t){
      const bf16x8 b = *(const bf16x8*)(Wf + (size_t)(((t * 4 + ks) * 64 + lane) * 8));
      acc[t] = __builtin_amdgcn_mfma_f32_16x16x32_bf16(a, b, acc[t], 0, 0, 0);
    }
  }

  const int quad = lane >> 4, col0 = lane & 15;
  float rs0 = 0.f, rs1 = 0.f, rs2 = 0.f, rs3 = 0.f;
  #pragma unroll
  for (int t = 0; t < 8; ++t){
    const int col = t * 16 + col0;
    const float bv = ldf(b1, col, isbf);
    const float wv = ldf(w2, col, isbf);
    rs0 = fmaf(fmaxf(acc[t][0] + bv, 0.f), wv, rs0);
    rs1 = fmaf(fmaxf(acc[t][1] + bv, 0.f), wv, rs1);
    rs2 = fmaf(fmaxf(acc[t][2] + bv, 0.f), wv, rs2);
    rs3 = fmaf(fmaxf(acc[t][3] + bv, 0.f), wv, rs3);
  }
  #pragma unroll
  for (int k = 1; k < 16; k <<= 1){
    rs0 += __shfl_xor(rs0, k);
    rs1 += __shfl_xor(rs1, k);
    rs2 += __shfl_xor(rs2, k);
    rs3 += __shfl_xor(rs3, k);
  }
  if (col0 < 4){
    const int row = m0 + quad * 4 + col0;
    if (row < n){
      float sc = (col0 == 0 ? rs0 : col0 == 1 ? rs1 : col0 == 2 ? rs2 : rs3) + ldf(b2, 0, isbf);
      if (mask[row] == 0) sc = -1e9f;
      s[row] = sc;
    }
  }
}

// ---- H[i] = (sum_{e->i} Ts[src] + Ts[i]) * dinv[i] + b[layer]; opt relu ----
__global__ __launch_bounds__(256) void k_gather(const u16* __restrict__ T, const int* __restrict__ boff,
                                                const int* __restrict__ eid, const float* __restrict__ dinv,
                                                const void* __restrict__ bias, int layer,
                                                u16* __restrict__ H, int n, int relu,
                                                const int* __restrict__ fl){
  const int wave = threadIdx.x >> 6, lane = threadIdx.x & 63;
  const int sub = lane >> 4, l16 = lane & 15;
  const int node = blockIdx.x * 16 + wave * 4 + sub;
  if (node >= n) return;
  const int isbf = *fl;
  const float di = dinv[node];
  const uint4 sv = ((const uint4*)(T + (size_t)node * 128))[l16];
  float acc0 = lo16(sv.x), acc1 = hi16(sv.x), acc2 = lo16(sv.y), acc3 = hi16(sv.y);
  float acc4 = lo16(sv.z), acc5 = hi16(sv.z), acc6 = lo16(sv.w), acc7 = hi16(sv.w);

  int j = boff[node];
  const int b1 = boff[node + 1];
  for (; j + 4 <= b1; j += 4){
    const int s0 = eid[j], s1 = eid[j + 1], s2 = eid[j + 2], s3 = eid[j + 3];
    const uint4 v0 = ((const uint4*)(T + (size_t)s0 * 128))[l16];
    const uint4 v1 = ((const uint4*)(T + (size_t)s1 * 128))[l16];
    const uint4 v2 = ((const uint4*)(T + (size_t)s2 * 128))[l16];
    const uint4 v3 = ((const uint4*)(T + (size_t)s3 * 128))[l16];
    acc0 += (lo16(v0.x) + lo16(v1.x)) + (lo16(v2.x) + lo16(v3.x));
    acc1 += (hi16(v0.x) + hi16(v1.x)) + (hi16(v2.x) + hi16(v3.x));
    acc2 += (lo16(v0.y) + lo16(v1.y)) + (lo16(v2.y) + lo16(v3.y));
    acc3 += (hi16(v0.y) + hi16(v1.y)) + (hi16(v2.y) + hi16(v3.y));
    acc4 += (lo16(v0.z) + lo16(v1.z)) + (lo16(v2.z) + lo16(v3.z));
    acc5 += (hi16(v0.z) + hi16(v1.z)) + (hi16(v2.z) + hi16(v3.z));
    acc6 += (lo16(v0.w) + lo16(v1.w)) + (lo16(v2.w) + lo16(v3.w));
    acc7 += (hi16(v0.w) + hi16(v1.w)) + (hi16(v2.w) + hi16(v3.w));
  }
  for (; j < b1; ++j){
    const uint4 v = ((const uint4*)(T + (size_t)eid[j] * 128))[l16];
    acc0 += lo16(v.x); acc1 += hi16(v.x);
    acc2 += lo16(v.y); acc3 += hi16(v.y);
    acc4 += lo16(v.z); acc5 += hi16(v.z);
    acc6 += lo16(v.w); acc7 += hi16(v.w);
  }
  const int bb = layer * 128 + l16 * 8;
  float h0 = fmaf(acc0, di, ldf(bias, bb + 0, isbf));
  float h1 = fmaf(acc1, di, ldf(bias, bb + 1, isbf));
  float h2 = fmaf(acc2, di, ldf(bias, bb + 2, isbf));
  float h3 = fmaf(acc3, di, ldf(bias, bb + 3, isbf));
  float h4 = fmaf(acc4, di, ldf(bias, bb + 4, isbf));
  float h5 = fmaf(acc5, di, ldf(bias, bb + 5, isbf));
  float h6 = fmaf(acc6, di, ldf(bias, bb + 6, isbf));
  float h7 = fmaf(acc7, di, ldf(bias, bb + 7, isbf));
  if (relu){
    h0 = fmaxf(h0, 0.f); h1 = fmaxf(h1, 0.f); h2 = fmaxf(h2, 0.f); h3 = fmaxf(h3, 0.f);
    h4 = fmaxf(h4, 0.f); h5 = fmaxf(h5, 0.f); h6 = fmaxf(h6, 0.f); h7 = fmaxf(h7, 0.f);
  }
  uint4 o;
  o.x = pack2(h0, h1); o.y = pack2(h2, h3); o.z = pack2(h4, h5); o.w = pack2(h6, h7);
  ((uint4*)(H + (size_t)node * 128))[l16] = o;
}

// ---- per-graph softmax: wave per graph, contiguous segment [goff[g], goff[g+1]) ----
__global__ __launch_bounds__(256) void k_gsm(const float* __restrict__ s, const int* __restrict__ goff,
                                             void* __restrict__ out, int G, const int* __restrict__ fl){
  const int g = blockIdx.x * 4 + (threadIdx.x >> 6);
  if (g >= G) return;
  const int lane = threadIdx.x & 63;
  const int i0 = goff[g], i1 = goff[g + 1];
  if (i0 >= i1) return;
  float m = -3.4e38f;
  for (int j = i0 + lane; j < i1; j += 64) m = fmaxf(m, s[j]);
  #pragma unroll
  for (int k = 32; k; k >>= 1) m = fmaxf(m, __shfl_xor(m, k));
  float zz = 0.f;
  for (int j = i0 + lane; j < i1; j += 64) zz += expf(s[j] - m);
  #pragma unroll
  for (int k = 32; k; k >>= 1) zz += __shfl_xor(zz, k);
  const float rz = 1.f / zz;
  const int isbf = *fl;
  for (int j = i0 + lane; j < i1; j += 64){
    const float v = expf(s[j] - m) * rz;
    if (isbf) ((u16*)out)[j] = ftobf(v);
    else      ((float*)out)[j] = v;
  }
}

extern "C" void kernel_launch(void* const* d_in, const int* in_sizes, int n_in,
                              void* d_out, int out_size, void* d_ws, size_t ws_size,
                              hipStream_t stream){
  const void* x    = d_in[0];
  const int* ei    = (const int*)d_in[1];
  const int* batch = (const int*)d_in[2];
  const int* mask  = (const int*)d_in[3];
  const void* gw   = d_in[4];
  const void* gb   = d_in[5];
  const void* l1w  = d_in[6];
  const void* l1b  = d_in[7];
  const void* l2w  = d_in[8];
  const void* l2b  = d_in[9];

  const int N = in_sizes[2];
  const int E = in_sizes[1] / 2;
  const int D = 128;
  const int L = in_sizes[4] / (D * D);
  const int G = 1000;   // from reference; not derivable from sizes

  char* p = (char*)d_ws;
  u16*  Hb    = (u16*)p;   p += (size_t)N * D * sizeof(u16);
  u16*  Tb    = (u16*)p;   p += (size_t)N * D * sizeof(u16);
  u16*  Wf    = (u16*)p;   p += (size_t)(L + 1) * D * D * sizeof(u16);
  float* dinv = (float*)p; p += (size_t)N * sizeof(float);
  float* sbuf = (float*)p; p += (size_t)N * sizeof(float);
  int*  cnt   = (int*)p;   p += (size_t)N * sizeof(int);
  int*  boff  = (int*)p;   p += (size_t)(N + 1) * sizeof(int);
  int*  bsum  = (int*)p;   p += 1024 * sizeof(int);
  int*  eid   = (int*)p;   p += (size_t)E * sizeof(int);
  int*  goff  = (int*)p;   p += (size_t)(G + 1) * sizeof(int);
  int*  flag  = (int*)p;   p += 256;

  const int* src  = ei;
  const int* dstp = ei + E;

  hipMemsetAsync(cnt, 0, (size_t)N * sizeof(int), stream);

  const int nb1 = (N + 255) / 256;
  const int mmg = (N + 127) / 128;
  const int ndg = (N + 15) / 16;
  const int n8  = N * D / 8;

  k_prep<<<(L + 1) + (n8 + 255) / 256, 256, 0, stream>>>(gw, l1w, x, Wf, Hb, L, n8, flag);
  k_count<<<(E + 255) / 256, 256, 0, stream>>>(dstp, cnt, E);
  k_scan1<<<nb1, 256, 0, stream>>>(cnt, boff, bsum, dinv, N);
  k_scan3<<<nb1, 256, 0, stream>>>(boff, bsum, nb1, N, E, batch, goff, G);
  k_fill<<<(E + 255) / 256, 256, 0, stream>>>(src, dstp, cnt, boff, eid, E);

  for (int l = 0; l < L; ++l){
    k_mm<<<mmg, 256, 0, stream>>>(x, Hb, (l == 0) ? 1 : 0, Wf + (size_t)l * D * D, dinv, Tb, N, flag);
    k_gather<<<ndg, 256, 0, stream>>>(Tb, boff, eid, dinv, gb, l, Hb, N, (l < L - 1) ? 1 : 0, flag);
  }
  k_mmhead<<<(N + 63) / 64, 256, 0, stream>>>(Hb, Wf + (size_t)L * D * D, l1b, l2w, l2b, mask, sbuf, N, flag);
  k_gsm<<<(G + 3) / 4, 256, 0, stream>>>(sbuf, goff, d_out, G, flag);
}

// Round 8
// 368.259 us; speedup vs baseline: 1.1326x; 1.1326x over previous
//
#include <hip/hip_runtime.h>
#include <hip/hip_bf16.h>

typedef unsigned int u32;
typedef unsigned short u16;
typedef __attribute__((ext_vector_type(8))) short bf16x8;
typedef __attribute__((ext_vector_type(4))) float f32x4;

__device__ __forceinline__ float u16tof(u16 u){ return __uint_as_float(((u32)u) << 16); }
__device__ __forceinline__ float lo16(u32 v){ return __uint_as_float(v << 16); }
__device__ __forceinline__ float hi16(u32 v){ return __uint_as_float(v & 0xffff0000u); }
__device__ __forceinline__ u16 ftobf(float f){
  u32 b = __float_as_uint(f);
  return (u16)((b + 0x7FFFu + ((b >> 16) & 1u)) >> 16);
}
__device__ __forceinline__ u32 pack2(float a, float b){
  return (u32)ftobf(a) | ((u32)ftobf(b) << 16);
}
__device__ __forceinline__ float ldf(const void* p, int i, int isbf){
  return isbf ? u16tof(((const u16*)p)[i]) : ((const float*)p)[i];
}

// ---- fused prep: blocks [0,L] dtype-detect + fragment-order weights;
//      blocks [L+1, L+1+cvtB) convert x->bf16 (fp32 path only);
//      blocks [L+1+cvtB, ...) degree-count over dst (independent work) ----
__global__ __launch_bounds__(256) void k_prep(const void* __restrict__ gw, const void* __restrict__ l1w,
                                              const void* __restrict__ x, u16* __restrict__ Wf,
                                              u16* __restrict__ Hb, int L, int n8, int cvtB,
                                              const int* __restrict__ dst, int* __restrict__ cntbuf, int nE,
                                              int* __restrict__ flag){
  const int b = blockIdx.x;
  if (b >= L + 1 + cvtB){
    int e = (b - (L + 1 + cvtB)) * 256 + threadIdx.x;
    if (e < nE) atomicAdd(&cntbuf[dst[e]], 1);
    return;
  }
  __shared__ int cnt;
  if (threadIdx.x == 0) cnt = 0;
  __syncthreads();
  if (b <= L){
    int local = 0;
    for (int i = threadIdx.x; i < 4096; i += 256){
      u32 e = (((const u32*)gw)[i] >> 7) & 0xFFu;
      if (e >= 100u && e < 127u) local++;
    }
    atomicAdd(&cnt, local);
    __syncthreads();
    const int isbf = (cnt > 2048) ? 1 : 0;
    if (b == 0 && threadIdx.x == 0) *flag = isbf;

    const void* src = (b < L) ? gw : l1w;
    const int sbase = (b < L) ? b * 16384 : 0;
    u16* dstp = Wf + (size_t)b * 16384;
    for (int g = threadIdx.x; g < 2048; g += 256){
      const int t = g >> 8, ks = (g >> 6) & 3, lane = g & 63;
      const int n = t * 16 + (lane & 15);
      const int k0 = ks * 32 + ((lane >> 4) << 3);
      u16* d = dstp + (size_t)g * 8;
      #pragma unroll
      for (int j = 0; j < 8; ++j){
        d[j] = ftobf(ldf(src, sbase + (k0 + j) * 128 + n, isbf));
      }
    }
  } else {
    u32 e = (((const u32*)gw)[threadIdx.x] >> 7) & 0xFFu;
    atomicAdd(&cnt, (e >= 100u && e < 127u) ? 1 : 0);
    __syncthreads();
    if (cnt > 128) return;            // bf16 path: k_mm reads x directly
    const int i = (b - (L + 1)) * 256 + threadIdx.x;
    if (i >= n8) return;
    const float4 a = ((const float4*)x)[i * 2];
    const float4 c = ((const float4*)x)[i * 2 + 1];
    u16* o = Hb + (size_t)i * 8;
    o[0] = ftobf(a.x); o[1] = ftobf(a.y); o[2] = ftobf(a.z); o[3] = ftobf(a.w);
    o[4] = ftobf(c.x); o[5] = ftobf(c.y); o[6] = ftobf(c.z); o[7] = ftobf(c.w);
  }
}

// ---- exclusive scan of cnt -> boff (block-local) ; also dinv = rsqrt(cnt+1) ----
__global__ __launch_bounds__(256) void k_scan1(const int* __restrict__ cnt, int* __restrict__ boff,
                                               int* __restrict__ bsum, float* __restrict__ dinv, int n){
  __shared__ int sm[256];
  int t = threadIdx.x;
  int i = blockIdx.x * 256 + t;
  int v = (i < n) ? cnt[i] : 0;
  if (i < n) dinv[i] = rsqrtf((float)v + 1.0f);
  sm[t] = v; __syncthreads();
  for (int off = 1; off < 256; off <<= 1){
    int add = (t >= off) ? sm[t - off] : 0;
    __syncthreads();
    sm[t] += add;
    __syncthreads();
  }
  if (i < n) boff[i] = sm[t] - v;
  if (t == 255) bsum[blockIdx.x] = sm[255];
}

// ---- boff fixup (each block redundantly scans bsum, nb<=512) + goff build ----
__global__ __launch_bounds__(256) void k_scan3(int* __restrict__ boff, const int* __restrict__ bsum, int nb,
                                               int n, int nE, const int* __restrict__ batch,
                                               int* __restrict__ goff, int G){
  __shared__ int sm[512];
  const int t = threadIdx.x;
  sm[t]       = (t < nb)       ? bsum[t]       : 0;
  sm[t + 256] = (t + 256 < nb) ? bsum[t + 256] : 0;
  __syncthreads();
  for (int off = 1; off < 512; off <<= 1){
    int v0 = (t >= off)       ? sm[t - off]       : 0;
    int v1 = (t + 256 >= off) ? sm[t + 256 - off] : 0;
    __syncthreads();
    sm[t] += v0; sm[t + 256] += v1;
    __syncthreads();
  }
  const int base = (blockIdx.x == 0) ? 0 : sm[blockIdx.x - 1];

  int i = blockIdx.x * 256 + t;
  if (i >= n) return;
  boff[i] += base;
  if (i == 0) boff[n] = nE;
  int b = batch[i];
  int prev = (i == 0) ? -1 : batch[i - 1];
  for (int g = prev + 1; g <= b; ++g) goff[g] = i;
  if (i == n - 1){
    for (int g = b + 1; g <= G; ++g) goff[g] = n;
  }
}

// ---- counting-sort edges by dst: eid[slot] = src ----
__global__ __launch_bounds__(256) void k_fill(const int* __restrict__ src, const int* __restrict__ dst,
                                              int* __restrict__ cnt, const int* __restrict__ boff,
                                              int* __restrict__ eid, int nE){
  int e = blockIdx.x * 256 + threadIdx.x;
  if (e >= nE) return;
  int d = dst[e];
  int old = atomicSub(&cnt[d], 1);
  eid[boff[d] + old - 1] = src[e];
}

// ---- GCN matmul: Ts[n,128] = (A[n,128] @ W) * dinv[row], bf16 out ----
// 16 rows/wave; W staged in LDS (ds_read B-frags, no per-MFMA global latency);
// LDS reused for the coalesced-store repack after a barrier.
__global__ __launch_bounds__(256) void k_mm(const void* __restrict__ X, const u16* __restrict__ Hb, int use_x,
                                            const u16* __restrict__ Wf, const float* __restrict__ dinv,
                                            u16* __restrict__ T, int n, const int* __restrict__ fl){
  __shared__ u16 smw[16384];   // 32 KB: staged Wf; aliased for repack after K-loop
  const int isbf = *fl;
  const u16* A = (use_x && isbf) ? (const u16*)X : Hb;
  {
    const uint4* s = (const uint4*)Wf;
    uint4* d = (uint4*)smw;
    for (int i = threadIdx.x; i < 2048; i += 256) d[i] = s[i];
  }
  __syncthreads();

  const int wave = threadIdx.x >> 6, lane = threadIdx.x & 63;
  const int m0 = blockIdx.x * 64 + wave * 16;
  int arow = m0 + (lane & 15); if (arow > n - 1) arow = n - 1;
  const u16* aptr = A + (size_t)arow * 128 + ((lane >> 4) << 3);

  f32x4 acc[8];
  #pragma unroll
  for (int t = 0; t < 8; ++t) acc[t] = (f32x4){0.f, 0.f, 0.f, 0.f};

  #pragma unroll
  for (int ks = 0; ks < 4; ++ks){
    const bf16x8 a = *(const bf16x8*)(aptr + ks * 32);
    #pragma unroll
    for (int t = 0; t < 8; ++t){
      const bf16x8 b = *(const bf16x8*)(smw + (size_t)(((t * 4 + ks) * 64 + lane) * 8));
      acc[t] = __builtin_amdgcn_mfma_f32_16x16x32_bf16(a, b, acc[t], 0, 0, 0);
    }
  }
  __syncthreads();   // all waves done reading Wf before aliasing

  const int quad = lane >> 4, col0 = lane & 15;
  float dv[4];
  #pragma unroll
  for (int r = 0; r < 4; ++r){
    const int row = m0 + quad * 4 + r;
    dv[r] = (row < n) ? dinv[row] : 0.f;
  }
  u16* my = smw + wave * 2112;          // 16*132 per wave, wave-private
  #pragma unroll
  for (int t = 0; t < 8; ++t){
    #pragma unroll
    for (int r = 0; r < 4; ++r){
      my[(quad * 4 + r) * 132 + t * 16 + col0] = ftobf(acc[t][r] * dv[r]);
    }
  }
  #pragma unroll
  for (int i = 0; i < 4; ++i){
    const int row = i * 4 + (lane >> 4);
    const int grow = m0 + row;
    const int c8 = (lane & 15) * 8;
    if (grow < n){
      const u16* s = &my[row * 132 + c8];
      uint2 lo = *(const uint2*)(s);
      uint2 hi = *(const uint2*)(s + 4);
      *(uint4*)&T[(size_t)grow * 128 + c8] = make_uint4(lo.x, lo.y, hi.x, hi.y);
    }
  }
}

// ---- fused head: s = relu(A@W1 + b1).w2 + b2, mask, write s; W1 staged in LDS ----
__global__ __launch_bounds__(256) void k_mmhead(const u16* __restrict__ Hb, const u16* __restrict__ Wf,
                                                const void* __restrict__ b1, const void* __restrict__ w2,
                                                const void* __restrict__ b2, const int* __restrict__ mask,
                                                float* __restrict__ s, int n, const int* __restrict__ fl){
  __shared__ u16 smw[16384];
  const int isbf = *fl;
  {
    const uint4* sp = (const uint4*)Wf;
    uint4* d = (uint4*)smw;
    for (int i = threadIdx.x; i < 2048; i += 256) d[i] = sp[i];
  }
  __syncthreads();

  const int wave = threadIdx.x >> 6, lane = threadIdx.x & 63;
  const int m0 = blockIdx.x * 64 + wave * 16;
  int arow = m0 + (lane & 15); if (arow > n - 1) arow = n - 1;
  const u16* aptr = Hb + (size_t)arow * 128 + ((lane >> 4) << 3);

  f32x4 acc[8];
  #pragma unroll
  for (int t = 0; t < 8; ++t) acc[t] = (f32x4){0.f, 0.f, 0.f, 0.f};

  #pragma unroll
  for (int ks = 0; ks < 4; ++ks){
    const bf16x8 a = *(const bf16x8*)(aptr + ks * 32);
    #pragma unroll
    for (int t = 0; t < 8; ++t){
      const bf16x8 b = *(const bf16x8*)(smw + (size_t)(((t * 4 + ks) * 64 + lane) * 8));
      acc[t] = __builtin_amdgcn_mfma_f32_16x16x32_bf16(a, b, acc[t], 0, 0, 0);
    }
  }

  const int quad = lane >> 4, col0 = lane & 15;
  float rs0 = 0.f, rs1 = 0.f, rs2 = 0.f, rs3 = 0.f;
  #pragma unroll
  for (int t = 0; t < 8; ++t){
    const int col = t * 16 + col0;
    const float bv = ldf(b1, col, isbf);
    const float wv = ldf(w2, col, isbf);
    rs0 = fmaf(fmaxf(acc[t][0] + bv, 0.f), wv, rs0);
    rs1 = fmaf(fmaxf(acc[t][1] + bv, 0.f), wv, rs1);
    rs2 = fmaf(fmaxf(acc[t][2] + bv, 0.f), wv, rs2);
    rs3 = fmaf(fmaxf(acc[t][3] + bv, 0.f), wv, rs3);
  }
  #pragma unroll
  for (int k = 1; k < 16; k <<= 1){
    rs0 += __shfl_xor(rs0, k);
    rs1 += __shfl_xor(rs1, k);
    rs2 += __shfl_xor(rs2, k);
    rs3 += __shfl_xor(rs3, k);
  }
  if (col0 < 4){
    const int row = m0 + quad * 4 + col0;
    if (row < n){
      float sc = (col0 == 0 ? rs0 : col0 == 1 ? rs1 : col0 == 2 ? rs2 : rs3) + ldf(b2, 0, isbf);
      if (mask[row] == 0) sc = -1e9f;
      s[row] = sc;
    }
  }
}

// ---- H[i] = (sum_{e->i} Ts[src] + Ts[i]) * dinv[i] + b[layer]; opt relu ----
__global__ __launch_bounds__(256) void k_gather(const u16* __restrict__ T, const int* __restrict__ boff,
                                                const int* __restrict__ eid, const float* __restrict__ dinv,
                                                const void* __restrict__ bias, int layer,
                                                u16* __restrict__ H, int n, int relu,
                                                const int* __restrict__ fl){
  const int wave = threadIdx.x >> 6, lane = threadIdx.x & 63;
  const int sub = lane >> 4, l16 = lane & 15;
  const int node = blockIdx.x * 16 + wave * 4 + sub;
  if (node >= n) return;
  const int isbf = *fl;
  const float di = dinv[node];
  const uint4 sv = ((const uint4*)(T + (size_t)node * 128))[l16];
  float acc0 = lo16(sv.x), acc1 = hi16(sv.x), acc2 = lo16(sv.y), acc3 = hi16(sv.y);
  float acc4 = lo16(sv.z), acc5 = hi16(sv.z), acc6 = lo16(sv.w), acc7 = hi16(sv.w);

  int j = boff[node];
  const int b1 = boff[node + 1];
  for (; j + 4 <= b1; j += 4){
    const int s0 = eid[j], s1 = eid[j + 1], s2 = eid[j + 2], s3 = eid[j + 3];
    const uint4 v0 = ((const uint4*)(T + (size_t)s0 * 128))[l16];
    const uint4 v1 = ((const uint4*)(T + (size_t)s1 * 128))[l16];
    const uint4 v2 = ((const uint4*)(T + (size_t)s2 * 128))[l16];
    const uint4 v3 = ((const uint4*)(T + (size_t)s3 * 128))[l16];
    acc0 += (lo16(v0.x) + lo16(v1.x)) + (lo16(v2.x) + lo16(v3.x));
    acc1 += (hi16(v0.x) + hi16(v1.x)) + (hi16(v2.x) + hi16(v3.x));
    acc2 += (lo16(v0.y) + lo16(v1.y)) + (lo16(v2.y) + lo16(v3.y));
    acc3 += (hi16(v0.y) + hi16(v1.y)) + (hi16(v2.y) + hi16(v3.y));
    acc4 += (lo16(v0.z) + lo16(v1.z)) + (lo16(v2.z) + lo16(v3.z));
    acc5 += (hi16(v0.z) + hi16(v1.z)) + (hi16(v2.z) + hi16(v3.z));
    acc6 += (lo16(v0.w) + lo16(v1.w)) + (lo16(v2.w) + lo16(v3.w));
    acc7 += (hi16(v0.w) + hi16(v1.w)) + (hi16(v2.w) + hi16(v3.w));
  }
  for (; j < b1; ++j){
    const uint4 v = ((const uint4*)(T + (size_t)eid[j] * 128))[l16];
    acc0 += lo16(v.x); acc1 += hi16(v.x);
    acc2 += lo16(v.y); acc3 += hi16(v.y);
    acc4 += lo16(v.z); acc5 += hi16(v.z);
    acc6 += lo16(v.w); acc7 += hi16(v.w);
  }
  const int bb = layer * 128 + l16 * 8;
  float h0 = fmaf(acc0, di, ldf(bias, bb + 0, isbf));
  float h1 = fmaf(acc1, di, ldf(bias, bb + 1, isbf));
  float h2 = fmaf(acc2, di, ldf(bias, bb + 2, isbf));
  float h3 = fmaf(acc3, di, ldf(bias, bb + 3, isbf));
  float h4 = fmaf(acc4, di, ldf(bias, bb + 4, isbf));
  float h5 = fmaf(acc5, di, ldf(bias, bb + 5, isbf));
  float h6 = fmaf(acc6, di, ldf(bias, bb + 6, isbf));
  float h7 = fmaf(acc7, di, ldf(bias, bb + 7, isbf));
  if (relu){
    h0 = fmaxf(h0, 0.f); h1 = fmaxf(h1, 0.f); h2 = fmaxf(h2, 0.f); h3 = fmaxf(h3, 0.f);
    h4 = fmaxf(h4, 0.f); h5 = fmaxf(h5, 0.f); h6 = fmaxf(h6, 0.f); h7 = fmaxf(h7, 0.f);
  }
  uint4 o;
  o.x = pack2(h0, h1); o.y = pack2(h2, h3); o.z = pack2(h4, h5); o.w = pack2(h6, h7);
  ((uint4*)(H + (size_t)node * 128))[l16] = o;
}

// ---- per-graph softmax: wave per graph, contiguous segment [goff[g], goff[g+1]) ----
__global__ __launch_bounds__(256) void k_gsm(const float* __restrict__ s, const int* __restrict__ goff,
                                             void* __restrict__ out, int G, const int* __restrict__ fl){
  const int g = blockIdx.x * 4 + (threadIdx.x >> 6);
  if (g >= G) return;
  const int lane = threadIdx.x & 63;
  const int i0 = goff[g], i1 = goff[g + 1];
  if (i0 >= i1) return;
  float m = -3.4e38f;
  for (int j = i0 + lane; j < i1; j += 64) m = fmaxf(m, s[j]);
  #pragma unroll
  for (int k = 32; k; k >>= 1) m = fmaxf(m, __shfl_xor(m, k));
  float zz = 0.f;
  for (int j = i0 + lane; j < i1; j += 64) zz += expf(s[j] - m);
  #pragma unroll
  for (int k = 32; k; k >>= 1) zz += __shfl_xor(zz, k);
  const float rz = 1.f / zz;
  const int isbf = *fl;
  for (int j = i0 + lane; j < i1; j += 64){
    const float v = expf(s[j] - m) * rz;
    if (isbf) ((u16*)out)[j] = ftobf(v);
    else      ((float*)out)[j] = v;
  }
}

extern "C" void kernel_launch(void* const* d_in, const int* in_sizes, int n_in,
                              void* d_out, int out_size, void* d_ws, size_t ws_size,
                              hipStream_t stream){
  const void* x    = d_in[0];
  const int* ei    = (const int*)d_in[1];
  const int* batch = (const int*)d_in[2];
  const int* mask  = (const int*)d_in[3];
  const void* gw   = d_in[4];
  const void* gb   = d_in[5];
  const void* l1w  = d_in[6];
  const void* l1b  = d_in[7];
  const void* l2w  = d_in[8];
  const void* l2b  = d_in[9];

  const int N = in_sizes[2];
  const int E = in_sizes[1] / 2;
  const int D = 128;
  const int L = in_sizes[4] / (D * D);
  const int G = 1000;   // from reference; not derivable from sizes

  char* p = (char*)d_ws;
  u16*  Hb    = (u16*)p;   p += (size_t)N * D * sizeof(u16);
  u16*  Tb    = (u16*)p;   p += (size_t)N * D * sizeof(u16);
  u16*  Wf    = (u16*)p;   p += (size_t)(L + 1) * D * D * sizeof(u16);
  float* dinv = (float*)p; p += (size_t)N * sizeof(float);
  float* sbuf = (float*)p; p += (size_t)N * sizeof(float);
  int*  cnt   = (int*)p;   p += (size_t)N * sizeof(int);
  int*  boff  = (int*)p;   p += (size_t)(N + 1) * sizeof(int);
  int*  bsum  = (int*)p;   p += 1024 * sizeof(int);
  int*  eid   = (int*)p;   p += (size_t)E * sizeof(int);
  int*  goff  = (int*)p;   p += (size_t)(G + 1) * sizeof(int);
  int*  flag  = (int*)p;   p += 256;

  const int* src  = ei;
  const int* dstp = ei + E;

  hipMemsetAsync(cnt, 0, (size_t)N * sizeof(int), stream);

  const int nb1 = (N + 255) / 256;
  const int mmg = (N + 63) / 64;
  const int ndg = (N + 15) / 16;
  const int n8  = N * D / 8;
  const int cvtB = (n8 + 255) / 256;
  const int cntB = (E + 255) / 256;

  k_prep<<<(L + 1) + cvtB + cntB, 256, 0, stream>>>(gw, l1w, x, Wf, Hb, L, n8, cvtB, dstp, cnt, E, flag);
  k_scan1<<<nb1, 256, 0, stream>>>(cnt, boff, bsum, dinv, N);
  k_scan3<<<nb1, 256, 0, stream>>>(boff, bsum, nb1, N, E, batch, goff, G);
  k_fill<<<cntB, 256, 0, stream>>>(src, dstp, cnt, boff, eid, E);

  for (int l = 0; l < L; ++l){
    k_mm<<<mmg, 256, 0, stream>>>(x, Hb, (l == 0) ? 1 : 0, Wf + (size_t)l * D * D, dinv, Tb, N, flag);
    k_gather<<<ndg, 256, 0, stream>>>(Tb, boff, eid, dinv, gb, l, Hb, N, (l < L - 1) ? 1 : 0, flag);
  }
  k_mmhead<<<mmg, 256, 0, stream>>>(Hb, Wf + (size_t)L * D * D, l1b, l2w, l2b, mask, sbuf, N, flag);
  k_gsm<<<(G + 3) / 4, 256, 0, stream>>>(sbuf, goff, d_out, G, flag);
}

// Round 9
// 335.298 us; speedup vs baseline: 1.2439x; 1.0983x over previous
//
#include <hip/hip_runtime.h>
#include <hip/hip_bf16.h>

typedef unsigned int u32;
typedef unsigned short u16;
typedef __attribute__((ext_vector_type(8))) short bf16x8;
typedef __attribute__((ext_vector_type(4))) float f32x4;

__device__ __forceinline__ float u16tof(u16 u){ return __uint_as_float(((u32)u) << 16); }
__device__ __forceinline__ float lo16(u32 v){ return __uint_as_float(v << 16); }
__device__ __forceinline__ float hi16(u32 v){ return __uint_as_float(v & 0xffff0000u); }
__device__ __forceinline__ u16 ftobf(float f){
  u32 b = __float_as_uint(f);
  return (u16)((b + 0x7FFFu + ((b >> 16) & 1u)) >> 16);
}
__device__ __forceinline__ u32 pack2(float a, float b){
  return (u32)ftobf(a) | ((u32)ftobf(b) << 16);
}
__device__ __forceinline__ float ldf(const void* p, int i, int isbf){
  return isbf ? u16tof(((const u16*)p)[i]) : ((const float*)p)[i];
}

// ---- fused prep. Block ranges (branch is blockIdx-uniform):
//  [0, L]                      : dtype-detect + fragment-order weights
//  [L+1, L+1+cvtB)             : x -> bf16 (fp32 path only; cheap self-detect)
//  [L+1+cvtB, +goffB)          : goff[g] = first node of graph g (batch sorted)
//  [histStart, histStart+256)  : per-block LDS histogram of dst>>9 buckets ----
__global__ __launch_bounds__(256) void k_prep(const void* __restrict__ gw, const void* __restrict__ l1w,
                                              const void* __restrict__ x, u16* __restrict__ Wf,
                                              u16* __restrict__ Hb, int L, int n8, int cvtB, int goffB,
                                              const int* __restrict__ batch, int* __restrict__ goff,
                                              int N, int G,
                                              const int* __restrict__ dst, int* __restrict__ hist,
                                              int nE, int chunk, int* __restrict__ flag){
  __shared__ int sh[256];
  const int b = blockIdx.x;
  const int t = threadIdx.x;
  const int histStart = L + 1 + cvtB + goffB;

  if (b >= histStart){                       // ---- edge-bucket histogram (LDS atomics only)
    sh[t] = 0; __syncthreads();
    const int blk = b - histStart;
    const int e0 = blk * chunk, e1 = min(e0 + chunk, nE);
    for (int e = e0 + t; e < e1; e += 256) atomicAdd(&sh[dst[e] >> 9], 1);
    __syncthreads();
    hist[blk * 256 + t] = sh[t];
    return;
  }
  if (b >= L + 1 + cvtB){                    // ---- goff build
    const int i = (b - (L + 1 + cvtB)) * 256 + t;
    if (i >= N) return;
    const int bt = batch[i];
    const int prev = (i == 0) ? -1 : batch[i - 1];
    for (int g = prev + 1; g <= bt; ++g) goff[g] = i;
    if (i == N - 1){ for (int g = bt + 1; g <= G; ++g) goff[g] = N; }
    return;
  }
  if (t == 0) sh[0] = 0;
  __syncthreads();
  if (b <= L){                               // ---- weight prep (full dtype detect)
    int local = 0;
    for (int i = t; i < 4096; i += 256){
      u32 e = (((const u32*)gw)[i] >> 7) & 0xFFu;
      if (e >= 100u && e < 127u) local++;
    }
    atomicAdd(&sh[0], local);
    __syncthreads();
    const int isbf = (sh[0] > 2048) ? 1 : 0;
    if (b == 0 && t == 0) *flag = isbf;

    const void* src = (b < L) ? gw : l1w;
    const int sbase = (b < L) ? b * 16384 : 0;
    u16* dstp = Wf + (size_t)b * 16384;
    for (int g = t; g < 2048; g += 256){
      const int tt = g >> 8, ks = (g >> 6) & 3, lane = g & 63;
      const int n = tt * 16 + (lane & 15);
      const int k0 = ks * 32 + ((lane >> 4) << 3);
      u16* d = dstp + (size_t)g * 8;
      #pragma unroll
      for (int j = 0; j < 8; ++j){
        d[j] = ftobf(ldf(src, sbase + (k0 + j) * 128 + n, isbf));
      }
    }
  } else {                                   // ---- cvt (fp32 path only)
    u32 e = (((const u32*)gw)[t] >> 7) & 0xFFu;
    atomicAdd(&sh[0], (e >= 100u && e < 127u) ? 1 : 0);
    __syncthreads();
    if (sh[0] > 128) return;                 // bf16 path: k_mm reads x directly
    const int i = (b - (L + 1)) * 256 + t;
    if (i >= n8) return;
    const float4 a = ((const float4*)x)[i * 2];
    const float4 c = ((const float4*)x)[i * 2 + 1];
    u16* o = Hb + (size_t)i * 8;
    o[0] = ftobf(a.x); o[1] = ftobf(a.y); o[2] = ftobf(a.z); o[3] = ftobf(a.w);
    o[4] = ftobf(c.x); o[5] = ftobf(c.y); o[6] = ftobf(c.z); o[7] = ftobf(c.w);
  }
}

// ---- column-scan of hist[256 blocks][256 buckets] -> per-block bases + bucket offsets bb ----
__global__ __launch_bounds__(256) void k_hscan(int* __restrict__ hist, int* __restrict__ bb, int nE){
  const int t = threadIdx.x;
  int run = 0;
  for (int j = 0; j < 256; ++j){
    const int v = hist[j * 256 + t];
    hist[j * 256 + t] = run;
    run += v;
  }
  __shared__ int sm[256];
  sm[t] = run; __syncthreads();
  for (int off = 1; off < 256; off <<= 1){
    int a = (t >= off) ? sm[t - off] : 0;
    __syncthreads();
    sm[t] += a;
    __syncthreads();
  }
  bb[t] = sm[t] - run;
  if (t == 255) bb[256] = nE;
}

// ---- scatter edges to bucket-sorted tmpe (same edge ranges as hist blocks) ----
__global__ __launch_bounds__(256) void k_scatter(const int* __restrict__ src, const int* __restrict__ dst,
                                                 const int* __restrict__ hist, const int* __restrict__ bb,
                                                 int2* __restrict__ tmpe, int nE, int chunk){
  __shared__ int base[256];
  const int blk = blockIdx.x, t = threadIdx.x;
  base[t] = bb[t] + hist[blk * 256 + t];
  __syncthreads();
  const int e0 = blk * chunk, e1 = min(e0 + chunk, nE);
  for (int e = e0 + t; e < e1; e += 256){
    const int d = dst[e];
    const int pos = atomicAdd(&base[d >> 9], 1);
    tmpe[pos] = make_int2(src[e], d);
  }
}

// ---- per-bucket local counting sort: boff, dinv, eid (all LDS atomics, coalesced writes) ----
__global__ __launch_bounds__(256) void k_local(const int2* __restrict__ tmpe, const int* __restrict__ bb,
                                               int* __restrict__ boff, int* __restrict__ eid,
                                               float* __restrict__ dinv, int N, int nE, int nbkt){
  __shared__ int hcnt[512];
  __shared__ int hoff[512];
  const int b = blockIdx.x, t = threadIdx.x;
  const int n0 = b << 9;
  const int n1 = min(n0 + 512, N);
  const int nn = n1 - n0;
  const int e0 = bb[b], e1 = bb[b + 1];
  hcnt[t] = 0; hcnt[t + 256] = 0;
  __syncthreads();
  for (int e = e0 + t; e < e1; e += 256) atomicAdd(&hcnt[tmpe[e].y - n0], 1);
  __syncthreads();
  const int v0 = hcnt[t], v1 = hcnt[t + 256];
  hoff[t] = v0; hoff[t + 256] = v1;
  __syncthreads();
  for (int off = 1; off < 512; off <<= 1){
    int a0 = (t >= off) ? hoff[t - off] : 0;
    int a1 = (t + 256 >= off) ? hoff[t + 256 - off] : 0;
    __syncthreads();
    hoff[t] += a0; hoff[t + 256] += a1;
    __syncthreads();
  }
  const int ex0 = hoff[t] - v0 + e0;          // absolute exclusive offsets
  const int ex1 = hoff[t + 256] - v1 + e0;
  if (t < nn){       boff[n0 + t] = ex0;        dinv[n0 + t] = rsqrtf((float)v0 + 1.0f); }
  if (t + 256 < nn){ boff[n0 + t + 256] = ex1;  dinv[n0 + t + 256] = rsqrtf((float)v1 + 1.0f); }
  if (b == nbkt - 1 && t == 0) boff[N] = nE;
  __syncthreads();
  hoff[t] = ex0; hoff[t + 256] = ex1;
  __syncthreads();
  for (int e = e0 + t; e < e1; e += 256){
    const int2 pr = tmpe[e];
    const int pos = atomicAdd(&hoff[pr.y - n0], 1);
    eid[pos] = pr.x;
  }
}

// ---- GCN matmul: Ts[n,128] = (A[n,128] @ W) * dinv[row], bf16 out ----
// 16 rows/wave; W staged in LDS; LDS reused for the coalesced-store repack.
__global__ __launch_bounds__(256) void k_mm(const void* __restrict__ X, const u16* __restrict__ Hb, int use_x,
                                            const u16* __restrict__ Wf, const float* __restrict__ dinv,
                                            u16* __restrict__ T, int n, const int* __restrict__ fl){
  __shared__ u16 smw[16384];
  const int isbf = *fl;
  const u16* A = (use_x && isbf) ? (const u16*)X : Hb;
  {
    const uint4* s = (const uint4*)Wf;
    uint4* d = (uint4*)smw;
    for (int i = threadIdx.x; i < 2048; i += 256) d[i] = s[i];
  }
  __syncthreads();

  const int wave = threadIdx.x >> 6, lane = threadIdx.x & 63;
  const int m0 = blockIdx.x * 64 + wave * 16;
  int arow = m0 + (lane & 15); if (arow > n - 1) arow = n - 1;
  const u16* aptr = A + (size_t)arow * 128 + ((lane >> 4) << 3);

  f32x4 acc[8];
  #pragma unroll
  for (int t = 0; t < 8; ++t) acc[t] = (f32x4){0.f, 0.f, 0.f, 0.f};

  #pragma unroll
  for (int ks = 0; ks < 4; ++ks){
    const bf16x8 a = *(const bf16x8*)(aptr + ks * 32);
    #pragma unroll
    for (int t = 0; t < 8; ++t){
      const bf16x8 b = *(const bf16x8*)(smw + (size_t)(((t * 4 + ks) * 64 + lane) * 8));
      acc[t] = __builtin_amdgcn_mfma_f32_16x16x32_bf16(a, b, acc[t], 0, 0, 0);
    }
  }
  __syncthreads();

  const int quad = lane >> 4, col0 = lane & 15;
  float dv[4];
  #pragma unroll
  for (int r = 0; r < 4; ++r){
    const int row = m0 + quad * 4 + r;
    dv[r] = (row < n) ? dinv[row] : 0.f;
  }
  u16* my = smw + wave * 2112;
  #pragma unroll
  for (int t = 0; t < 8; ++t){
    #pragma unroll
    for (int r = 0; r < 4; ++r){
      my[(quad * 4 + r) * 132 + t * 16 + col0] = ftobf(acc[t][r] * dv[r]);
    }
  }
  #pragma unroll
  for (int i = 0; i < 4; ++i){
    const int row = i * 4 + (lane >> 4);
    const int grow = m0 + row;
    const int c8 = (lane & 15) * 8;
    if (grow < n){
      const u16* s = &my[row * 132 + c8];
      uint2 lo = *(const uint2*)(s);
      uint2 hi = *(const uint2*)(s + 4);
      *(uint4*)&T[(size_t)grow * 128 + c8] = make_uint4(lo.x, lo.y, hi.x, hi.y);
    }
  }
}

// ---- fused head: s = relu(A@W1 + b1).w2 + b2, mask, write s; W1 staged in LDS ----
__global__ __launch_bounds__(256) void k_mmhead(const u16* __restrict__ Hb, const u16* __restrict__ Wf,
                                                const void* __restrict__ b1, const void* __restrict__ w2,
                                                const void* __restrict__ b2, const int* __restrict__ mask,
                                                float* __restrict__ s, int n, const int* __restrict__ fl){
  __shared__ u16 smw[16384];
  const int isbf = *fl;
  {
    const uint4* sp = (const uint4*)Wf;
    uint4* d = (uint4*)smw;
    for (int i = threadIdx.x; i < 2048; i += 256) d[i] = sp[i];
  }
  __syncthreads();

  const int wave = threadIdx.x >> 6, lane = threadIdx.x & 63;
  const int m0 = blockIdx.x * 64 + wave * 16;
  int arow = m0 + (lane & 15); if (arow > n - 1) arow = n - 1;
  const u16* aptr = Hb + (size_t)arow * 128 + ((lane >> 4) << 3);

  f32x4 acc[8];
  #pragma unroll
  for (int t = 0; t < 8; ++t) acc[t] = (f32x4){0.f, 0.f, 0.f, 0.f};

  #pragma unroll
  for (int ks = 0; ks < 4; ++ks){
    const bf16x8 a = *(const bf16x8*)(aptr + ks * 32);
    #pragma unroll
    for (int t = 0; t < 8; ++t){
      const bf16x8 b = *(const bf16x8*)(smw + (size_t)(((t * 4 + ks) * 64 + lane) * 8));
      acc[t] = __builtin_amdgcn_mfma_f32_16x16x32_bf16(a, b, acc[t], 0, 0, 0);
    }
  }

  const int quad = lane >> 4, col0 = lane & 15;
  float rs0 = 0.f, rs1 = 0.f, rs2 = 0.f, rs3 = 0.f;
  #pragma unroll
  for (int t = 0; t < 8; ++t){
    const int col = t * 16 + col0;
    const float bv = ldf(b1, col, isbf);
    const float wv = ldf(w2, col, isbf);
    rs0 = fmaf(fmaxf(acc[t][0] + bv, 0.f), wv, rs0);
    rs1 = fmaf(fmaxf(acc[t][1] + bv, 0.f), wv, rs1);
    rs2 = fmaf(fmaxf(acc[t][2] + bv, 0.f), wv, rs2);
    rs3 = fmaf(fmaxf(acc[t][3] + bv, 0.f), wv, rs3);
  }
  #pragma unroll
  for (int k = 1; k < 16; k <<= 1){
    rs0 += __shfl_xor(rs0, k);
    rs1 += __shfl_xor(rs1, k);
    rs2 += __shfl_xor(rs2, k);
    rs3 += __shfl_xor(rs3, k);
  }
  if (col0 < 4){
    const int row = m0 + quad * 4 + col0;
    if (row < n){
      float sc = (col0 == 0 ? rs0 : col0 == 1 ? rs1 : col0 == 2 ? rs2 : rs3) + ldf(b2, 0, isbf);
      if (mask[row] == 0) sc = -1e9f;
      s[row] = sc;
    }
  }
}

// ---- H[i] = (sum_{e->i} Ts[src] + Ts[i]) * dinv[i] + b[layer]; opt relu ----
__global__ __launch_bounds__(256) void k_gather(const u16* __restrict__ T, const int* __restrict__ boff,
                                                const int* __restrict__ eid, const float* __restrict__ dinv,
                                                const void* __restrict__ bias, int layer,
                                                u16* __restrict__ H, int n, int relu,
                                                const int* __restrict__ fl){
  const int wave = threadIdx.x >> 6, lane = threadIdx.x & 63;
  const int sub = lane >> 4, l16 = lane & 15;
  const int node = blockIdx.x * 16 + wave * 4 + sub;
  if (node >= n) return;
  const int isbf = *fl;
  const float di = dinv[node];
  const uint4 sv = ((const uint4*)(T + (size_t)node * 128))[l16];
  float acc0 = lo16(sv.x), acc1 = hi16(sv.x), acc2 = lo16(sv.y), acc3 = hi16(sv.y);
  float acc4 = lo16(sv.z), acc5 = hi16(sv.z), acc6 = lo16(sv.w), acc7 = hi16(sv.w);

  int j = boff[node];
  const int b1 = boff[node + 1];
  for (; j + 4 <= b1; j += 4){
    const int s0 = eid[j], s1 = eid[j + 1], s2 = eid[j + 2], s3 = eid[j + 3];
    const uint4 v0 = ((const uint4*)(T + (size_t)s0 * 128))[l16];
    const uint4 v1 = ((const uint4*)(T + (size_t)s1 * 128))[l16];
    const uint4 v2 = ((const uint4*)(T + (size_t)s2 * 128))[l16];
    const uint4 v3 = ((const uint4*)(T + (size_t)s3 * 128))[l16];
    acc0 += (lo16(v0.x) + lo16(v1.x)) + (lo16(v2.x) + lo16(v3.x));
    acc1 += (hi16(v0.x) + hi16(v1.x)) + (hi16(v2.x) + hi16(v3.x));
    acc2 += (lo16(v0.y) + lo16(v1.y)) + (lo16(v2.y) + lo16(v3.y));
    acc3 += (hi16(v0.y) + hi16(v1.y)) + (hi16(v2.y) + hi16(v3.y));
    acc4 += (lo16(v0.z) + lo16(v1.z)) + (lo16(v2.z) + lo16(v3.z));
    acc5 += (hi16(v0.z) + hi16(v1.z)) + (hi16(v2.z) + hi16(v3.z));
    acc6 += (lo16(v0.w) + lo16(v1.w)) + (lo16(v2.w) + lo16(v3.w));
    acc7 += (hi16(v0.w) + hi16(v1.w)) + (hi16(v2.w) + hi16(v3.w));
  }
  for (; j < b1; ++j){
    const uint4 v = ((const uint4*)(T + (size_t)eid[j] * 128))[l16];
    acc0 += lo16(v.x); acc1 += hi16(v.x);
    acc2 += lo16(v.y); acc3 += hi16(v.y);
    acc4 += lo16(v.z); acc5 += hi16(v.z);
    acc6 += lo16(v.w); acc7 += hi16(v.w);
  }
  const int bb = layer * 128 + l16 * 8;
  float h0 = fmaf(acc0, di, ldf(bias, bb + 0, isbf));
  float h1 = fmaf(acc1, di, ldf(bias, bb + 1, isbf));
  float h2 = fmaf(acc2, di, ldf(bias, bb + 2, isbf));
  float h3 = fmaf(acc3, di, ldf(bias, bb + 3, isbf));
  float h4 = fmaf(acc4, di, ldf(bias, bb + 4, isbf));
  float h5 = fmaf(acc5, di, ldf(bias, bb + 5, isbf));
  float h6 = fmaf(acc6, di, ldf(bias, bb + 6, isbf));
  float h7 = fmaf(acc7, di, ldf(bias, bb + 7, isbf));
  if (relu){
    h0 = fmaxf(h0, 0.f); h1 = fmaxf(h1, 0.f); h2 = fmaxf(h2, 0.f); h3 = fmaxf(h3, 0.f);
    h4 = fmaxf(h4, 0.f); h5 = fmaxf(h5, 0.f); h6 = fmaxf(h6, 0.f); h7 = fmaxf(h7, 0.f);
  }
  uint4 o;
  o.x = pack2(h0, h1); o.y = pack2(h2, h3); o.z = pack2(h4, h5); o.w = pack2(h6, h7);
  ((uint4*)(H + (size_t)node * 128))[l16] = o;
}

// ---- per-graph softmax: wave per graph, contiguous segment [goff[g], goff[g+1]) ----
__global__ __launch_bounds__(256) void k_gsm(const float* __restrict__ s, const int* __restrict__ goff,
                                             void* __restrict__ out, int G, const int* __restrict__ fl){
  const int g = blockIdx.x * 4 + (threadIdx.x >> 6);
  if (g >= G) return;
  const int lane = threadIdx.x & 63;
  const int i0 = goff[g], i1 = goff[g + 1];
  if (i0 >= i1) return;
  float m = -3.4e38f;
  for (int j = i0 + lane; j < i1; j += 64) m = fmaxf(m, s[j]);
  #pragma unroll
  for (int k = 32; k; k >>= 1) m = fmaxf(m, __shfl_xor(m, k));
  float zz = 0.f;
  for (int j = i0 + lane; j < i1; j += 64) zz += expf(s[j] - m);
  #pragma unroll
  for (int k = 32; k; k >>= 1) zz += __shfl_xor(zz, k);
  const float rz = 1.f / zz;
  const int isbf = *fl;
  for (int j = i0 + lane; j < i1; j += 64){
    const float v = expf(s[j] - m) * rz;
    if (isbf) ((u16*)out)[j] = ftobf(v);
    else      ((float*)out)[j] = v;
  }
}

extern "C" void kernel_launch(void* const* d_in, const int* in_sizes, int n_in,
                              void* d_out, int out_size, void* d_ws, size_t ws_size,
                              hipStream_t stream){
  const void* x    = d_in[0];
  const int* ei    = (const int*)d_in[1];
  const int* batch = (const int*)d_in[2];
  const int* mask  = (const int*)d_in[3];
  const void* gw   = d_in[4];
  const void* gb   = d_in[5];
  const void* l1w  = d_in[6];
  const void* l1b  = d_in[7];
  const void* l2w  = d_in[8];
  const void* l2b  = d_in[9];

  const int N = in_sizes[2];        // <= 131072 for the 512-node buckets (dst>>9)
  const int E = in_sizes[1] / 2;
  const int D = 128;
  const int L = in_sizes[4] / (D * D);
  const int G = 1000;   // from reference; not derivable from sizes

  char* p = (char*)d_ws;
  u16*  Hb    = (u16*)p;   p += (size_t)N * D * sizeof(u16);
  u16*  Tb    = (u16*)p;   p += (size_t)N * D * sizeof(u16);
  u16*  Wf    = (u16*)p;   p += (size_t)(L + 1) * D * D * sizeof(u16);
  float* dinv = (float*)p; p += (size_t)N * sizeof(float);
  float* sbuf = (float*)p; p += (size_t)N * sizeof(float);
  int*  boff  = (int*)p;   p += (size_t)(N + 1) * sizeof(int);
  int*  eid   = (int*)p;   p += (size_t)E * sizeof(int);
  int*  goff  = (int*)p;   p += (size_t)(G + 1) * sizeof(int);
  int*  hist  = (int*)p;   p += 256 * 256 * sizeof(int);
  int*  bb    = (int*)p;   p += 260 * sizeof(int);
  int2* tmpe  = (int2*)p;  p += (size_t)E * sizeof(int2);
  int*  flag  = (int*)p;   p += 256;

  const int* srcp = ei;
  const int* dstp = ei + E;

  const int mmg  = (N + 63) / 64;
  const int ndg  = (N + 15) / 16;
  const int n8   = N * D / 8;
  const int cvtB = (n8 + 255) / 256;
  const int goffB = (N + 255) / 256;
  const int chunk = (E + 255) / 256;
  const int nbkt  = (N + 511) / 512;

  k_prep<<<(L + 1) + cvtB + goffB + 256, 256, 0, stream>>>(gw, l1w, x, Wf, Hb, L, n8, cvtB, goffB,
                                                           batch, goff, N, G, dstp, hist, E, chunk, flag);
  k_hscan<<<1, 256, 0, stream>>>(hist, bb, E);
  k_scatter<<<256, 256, 0, stream>>>(srcp, dstp, hist, bb, tmpe, E, chunk);
  k_local<<<nbkt, 256, 0, stream>>>(tmpe, bb, boff, eid, dinv, N, E, nbkt);

  for (int l = 0; l < L; ++l){
    k_mm<<<mmg, 256, 0, stream>>>(x, Hb, (l == 0) ? 1 : 0, Wf + (size_t)l * D * D, dinv, Tb, N, flag);
    k_gather<<<ndg, 256, 0, stream>>>(Tb, boff, eid, dinv, gb, l, Hb, N, (l < L - 1) ? 1 : 0, flag);
  }
  k_mmhead<<<mmg, 256, 0, stream>>>(Hb, Wf + (size_t)L * D * D, l1b, l2w, l2b, mask, sbuf, N, flag);
  k_gsm<<<(G + 3) / 4, 256, 0, stream>>>(sbuf, goff, d_out, G, flag);
}